// Round 4
// baseline (239.931 us; speedup 1.0000x reference)
//
#include <hip/hip_runtime.h>
#include <cstdint>

constexpr int N_FEAT  = 8;
constexpr int E_FEAT  = 4;
constexpr int NUM_IN  = 2 * (N_FEAT + 2) + E_FEAT + 1;  // 25
constexpr int NUM_OUT = 2 * N_FEAT + E_FEAT;            // 20
constexpr int BLK     = 256;
constexpr int EPT     = 2;   // edges per thread

// Textual macros, NOT helper functions: a float[25] function parameter
// defeated SROA (arrays to scratch, VGPR=52, +41 MB spill traffic, 159 us).
// Macro params are named XA/YA/ee so they can never token-collide with the
// .x/.y/.z/.w member names (the round-3 compile failure).
#define LOAD_X(ee, XA)                                                      \
  do {                                                                      \
    const float4* a4_ = reinterpret_cast<const float4*>(a_data) + 2 * (size_t)(ee); \
    const float4* b4_ = reinterpret_cast<const float4*>(b_data) + 2 * (size_t)(ee); \
    float4 a0_ = a4_[0], a1_ = a4_[1];                                      \
    float4 b0_ = b4_[0], b1_ = b4_[1];                                      \
    float4 ev_ = reinterpret_cast<const float4*>(e_data)[(ee)];             \
    XA[0]  = r[(ee)];                                                       \
    XA[1]  = a0_.x; XA[2]  = a0_.y; XA[3]  = a0_.z; XA[4]  = a0_.w;         \
    XA[5]  = a1_.x; XA[6]  = a1_.y; XA[7]  = a1_.z; XA[8]  = a1_.w;         \
    XA[9]  = a_mat[(ee)];                                                   \
    XA[10] = a_inf[(ee)];                                                   \
    XA[11] = b0_.x; XA[12] = b0_.y; XA[13] = b0_.z; XA[14] = b0_.w;         \
    XA[15] = b1_.x; XA[16] = b1_.y; XA[17] = b1_.z; XA[18] = b1_.w;         \
    XA[19] = b_mat[(ee)];                                                   \
    XA[20] = b_inf[(ee)];                                                   \
    XA[21] = ev_.x; XA[22] = ev_.y; XA[23] = ev_.z; XA[24] = ev_.w;         \
  } while (0)

#define STORE_Y(ee, YA)                                                     \
  do {                                                                      \
    float4* o0_ = reinterpret_cast<float4*>(out) + 2 * (size_t)(ee);        \
    o0_[0] = make_float4(YA[0], YA[1], YA[2],  YA[3]);                      \
    o0_[1] = make_float4(YA[4], YA[5], YA[6],  YA[7]);                      \
    float4* o1_ = reinterpret_cast<float4*>(out + (size_t)8 * E) + 2 * (size_t)(ee); \
    o1_[0] = make_float4(YA[8],  YA[9],  YA[10], YA[11]);                   \
    o1_[1] = make_float4(YA[12], YA[13], YA[14], YA[15]);                   \
    reinterpret_cast<float4*>(out + (size_t)16 * E)[(ee)] =                 \
        make_float4(YA[16], YA[17], YA[18], YA[19]);                        \
  } while (0)

// EPT=2: each wave-uniform weight (SGPR-resident) feeds two independent FMA
// chains -> halves weight-fetch latency exposure per FLOP, doubles per-wave
// ILP. Peak liveness ~100 floats + ~20 transient gather regs. waves_per_eu
// (3,4) sets the VGPR cap to ~170 so the allocator has headroom (the (4,4)
// 128-cap was borderline and tipped the round-2 build into whole-array
// spill). ILP-for-TLP trade: 3 waves/EU min instead of 4.
__global__ __launch_bounds__(BLK)
__attribute__((amdgpu_waves_per_eu(3, 4)))
void edge_mlp(
    const float* __restrict__ r,
    const float* __restrict__ a_data,
    const float* __restrict__ a_mat,
    const float* __restrict__ a_inf,
    const float* __restrict__ b_data,
    const float* __restrict__ b_mat,
    const float* __restrict__ b_inf,
    const float* __restrict__ e_data,
    const float* __restrict__ W1,   // (25,25) row-major fp32
    const float* __restrict__ B1,   // (25,)
    const float* __restrict__ W2,   // (20,25) row-major
    const float* __restrict__ B2,   // (20,)
    float*       __restrict__ out,  // fp32, 3 segments concatenated
    int E) {
  const int tid  = threadIdx.x;
  const int base = blockIdx.x * (BLK * EPT);
  const int e0   = base + tid;
  if (e0 >= E) return;
  int e1         = base + BLK + tid;
  const bool p1  = (e1 < E);
  if (!p1) e1 = e0;   // clamp: tail block's second-edge loads stay in-bounds

  // ---- gather features for both edges (coalesced float4 loads) ----
  float x0[NUM_IN], x1[NUM_IN];
  LOAD_X(e0, x0);
  LOAD_X(e1, x1);

  // ---- layer 1: h = relu(W1 @ x + b1); one SGPR weight -> two FMA chains ----
  float h0[NUM_IN], h1[NUM_IN];
#pragma unroll
  for (int j = 0; j < NUM_IN; ++j) {
    const float* wr = W1 + j * NUM_IN;
    float acc0 = B1[j];
    float acc1 = acc0;
#pragma unroll
    for (int k = 0; k < NUM_IN; ++k) {
      const float w = wr[k];
      acc0 = fmaf(w, x0[k], acc0);
      acc1 = fmaf(w, x1[k], acc1);
    }
    h0[j] = fmaxf(acc0, 0.0f);
    h1[j] = fmaxf(acc1, 0.0f);
  }

  // ---- layer 2: y = relu(W2 @ h + b2) ----
  float y0[NUM_OUT], y1[NUM_OUT];
#pragma unroll
  for (int j = 0; j < NUM_OUT; ++j) {
    const float* wr = W2 + j * NUM_IN;
    float acc0 = B2[j];
    float acc1 = acc0;
#pragma unroll
    for (int k = 0; k < NUM_IN; ++k) {
      const float w = wr[k];
      acc0 = fmaf(w, h0[k], acc0);
      acc1 = fmaf(w, h1[k], acc1);
    }
    y0[j] = fmaxf(acc0, 0.0f);
    y1[j] = fmaxf(acc1, 0.0f);
  }

  // ---- store both edges ----
  STORE_Y(e0, y0);
  if (p1) STORE_Y(e1, y1);
}

extern "C" void kernel_launch(void* const* d_in, const int* in_sizes, int n_in,
                              void* d_out, int out_size, void* d_ws, size_t ws_size,
                              hipStream_t stream) {
  const float* r      = (const float*)d_in[0];
  const float* a_data = (const float*)d_in[1];
  const float* a_mat  = (const float*)d_in[2];
  const float* a_inf  = (const float*)d_in[3];
  const float* b_data = (const float*)d_in[4];
  const float* b_mat  = (const float*)d_in[5];
  const float* b_inf  = (const float*)d_in[6];
  const float* e_data = (const float*)d_in[7];
  const float* W1     = (const float*)d_in[8];
  const float* B1     = (const float*)d_in[9];
  const float* W2     = (const float*)d_in[10];
  const float* B2     = (const float*)d_in[11];
  int E = in_sizes[0];

  const int epb = BLK * EPT;  // edges per block
  edge_mlp<<<(E + epb - 1) / epb, BLK, 0, stream>>>(
      r, a_data, a_mat, a_inf, b_data, b_mat, b_inf, e_data,
      W1, B1, W2, B2, (float*)d_out, E);
}